// Round 1
// baseline (101.974 us; speedup 1.0000x reference)
//
#include <hip/hip_runtime.h>

// piecewise max-pool: conv [B, S=256, F=230] f32, positions [B,4] i32 -> out [B, 3*230] f32
// Per batch b: e1=pos[b][1], e2=pos[b][3]; max over s-ranges [0,e1), [e1,e2), [e2,S) per filter.
// e1/e2 are block-uniform -> three uniform-bound loops, no per-element piece tests.

constexpr int S    = 256;
constexpr int Fn   = 230;
constexpr int HALF = 115;            // Fn/2 float2 columns per row
constexpr float NEG = -1e30f;

__global__ __launch_bounds__(256) void pmax_kernel(
    const float* __restrict__ conv,
    const int*   __restrict__ pos,
    float*       __restrict__ out)
{
    const int b   = blockIdx.x;
    const int tid = threadIdx.x;
    const int e1  = pos[b * 4 + 1];
    const int e2  = pos[b * 4 + 3];
    const float* base = conv + (size_t)b * (S * Fn);

    // threads 0..114 -> row parity 0, threads 115..229 -> row parity 1; 230..255 idle
    const bool active = tid < 2 * HALF;
    const int  row    = (tid >= HALF) ? 1 : 0;
    const int  col    = tid - row * HALF;     // 0..114, owns filters 2col, 2col+1

    float m0x = NEG, m0y = NEG;
    float m1x = NEG, m1y = NEG;
    float m2x = NEG, m2y = NEG;

    if (active) {
        const float* p = base + 2 * col;   // 8-byte aligned: base 16B-aligned, row stride 920B

        // piece 0: s in [0, e1)
        for (int sb = 0; sb < e1; sb += 2) {
            const int s = sb + row;
            if (s < e1) {
                const float2 v = *(const float2*)(p + (size_t)s * Fn);
                m0x = fmaxf(m0x, v.x);
                m0y = fmaxf(m0y, v.y);
            }
        }
        // piece 1: s in [e1, e2)
        for (int sb = e1; sb < e2; sb += 2) {
            const int s = sb + row;
            if (s < e2) {
                const float2 v = *(const float2*)(p + (size_t)s * Fn);
                m1x = fmaxf(m1x, v.x);
                m1y = fmaxf(m1y, v.y);
            }
        }
        // piece 2: s in [e2, S)
        for (int sb = e2; sb < S; sb += 2) {
            const int s = sb + row;
            if (s < S) {
                const float2 v = *(const float2*)(p + (size_t)s * Fn);
                m2x = fmaxf(m2x, v.x);
                m2y = fmaxf(m2y, v.y);
            }
        }
    }

    // combine the two row-parities: threads 115..229 publish, 0..114 reduce + store
    __shared__ float red[6][HALF];
    if (active && row) {
        red[0][col] = m0x; red[1][col] = m0y;
        red[2][col] = m1x; red[3][col] = m1y;
        red[4][col] = m2x; red[5][col] = m2y;
    }
    __syncthreads();
    if (active && !row) {
        m0x = fmaxf(m0x, red[0][col]); m0y = fmaxf(m0y, red[1][col]);
        m1x = fmaxf(m1x, red[2][col]); m1y = fmaxf(m1y, red[3][col]);
        m2x = fmaxf(m2x, red[4][col]); m2y = fmaxf(m2y, red[5][col]);

        float* ob = out + (size_t)b * (3 * Fn);
        *(float2*)(ob + 0 * Fn + 2 * col) = make_float2(m0x, m0y);
        *(float2*)(ob + 1 * Fn + 2 * col) = make_float2(m1x, m1y);
        *(float2*)(ob + 2 * Fn + 2 * col) = make_float2(m2x, m2y);
    }
}

extern "C" void kernel_launch(void* const* d_in, const int* in_sizes, int n_in,
                              void* d_out, int out_size, void* d_ws, size_t ws_size,
                              hipStream_t stream)
{
    const float* conv = (const float*)d_in[0];
    const int*   pos  = (const int*)d_in[1];
    float*       out  = (float*)d_out;

    const int B = in_sizes[0] / (S * Fn);   // 2048
    pmax_kernel<<<B, 256, 0, stream>>>(conv, pos, out);
}

// Round 2
// 91.500 us; speedup vs baseline: 1.1145x; 1.1145x over previous
//
#include <hip/hip_runtime.h>

// piecewise max-pool: conv [B, S=256, F=230] f32, positions [B,4] i32 -> out [B, 3*230] f32
// Per batch b: e1=pos[b][1], e2=pos[b][3]; max over s-ranges [0,e1), [e1,e2), [e2,S).
//
// R2: single compile-time-trip-count loop (128 row-pairs) + branchless accumulator
// select. Constant bounds let the compiler unroll x8 and keep ~8 global_load_dwordx2
// in flight per wave (was: 3 runtime-bound loops -> ~1 load in flight -> 60% of HBM peak).

constexpr int S    = 256;
constexpr int Fn   = 230;
constexpr int HALF = 115;            // Fn/2 float2 columns per row
constexpr float NEG = -1e30f;

__global__ __launch_bounds__(256) void pmax_kernel(
    const float* __restrict__ conv,
    const int*   __restrict__ pos,
    float*       __restrict__ out)
{
    const int b   = blockIdx.x;
    const int tid = threadIdx.x;
    const int e1  = pos[b * 4 + 1];
    const int e2  = pos[b * 4 + 3];
    const float* base = conv + (size_t)b * (S * Fn);

    // threads 0..114 -> row parity 0, threads 115..229 -> row parity 1; 230..255 idle
    const bool active = tid < 2 * HALF;
    const int  row    = (tid >= HALF) ? 1 : 0;
    const int  col    = tid - row * HALF;     // 0..114, owns filters 2col, 2col+1

    float m0x = NEG, m0y = NEG;
    float m1x = NEG, m1y = NEG;
    float m2x = NEG, m2y = NEG;

    if (active) {
        const float* p = base + 2 * col + (size_t)row * Fn;  // 8-byte aligned
        // fold s = sb + row into the thresholds: s < e ⟺ sb < e - row
        const int a1 = e1 - row;
        const int a2 = e2 - row;

        #pragma unroll 8
        for (int sb = 0; sb < S; sb += 2) {          // compile-time trip count: 128
            const float2 v = *(const float2*)(p + (size_t)sb * Fn);
            const bool c1 = sb < a1;                 // s in piece 0
            const bool c2 = sb < a2;                 // s in piece 0 or 1
            float t0x = c1 ? v.x : NEG, t0y = c1 ? v.y : NEG;
            float t1x = c2 ? v.x : NEG, t1y = c2 ? v.y : NEG;
            t1x = c1 ? NEG : t1x;       t1y = c1 ? NEG : t1y;
            float t2x = c2 ? NEG : v.x, t2y = c2 ? NEG : v.y;
            m0x = fmaxf(m0x, t0x); m0y = fmaxf(m0y, t0y);
            m1x = fmaxf(m1x, t1x); m1y = fmaxf(m1y, t1y);
            m2x = fmaxf(m2x, t2x); m2y = fmaxf(m2y, t2y);
        }
    }

    // combine the two row-parities: threads 115..229 publish, 0..114 reduce + store
    __shared__ float red[6][HALF];
    if (active && row) {
        red[0][col] = m0x; red[1][col] = m0y;
        red[2][col] = m1x; red[3][col] = m1y;
        red[4][col] = m2x; red[5][col] = m2y;
    }
    __syncthreads();
    if (active && !row) {
        m0x = fmaxf(m0x, red[0][col]); m0y = fmaxf(m0y, red[1][col]);
        m1x = fmaxf(m1x, red[2][col]); m1y = fmaxf(m1y, red[3][col]);
        m2x = fmaxf(m2x, red[4][col]); m2y = fmaxf(m2y, red[5][col]);

        float* ob = out + (size_t)b * (3 * Fn);
        *(float2*)(ob + 0 * Fn + 2 * col) = make_float2(m0x, m0y);
        *(float2*)(ob + 1 * Fn + 2 * col) = make_float2(m1x, m1y);
        *(float2*)(ob + 2 * Fn + 2 * col) = make_float2(m2x, m2y);
    }
}

extern "C" void kernel_launch(void* const* d_in, const int* in_sizes, int n_in,
                              void* d_out, int out_size, void* d_ws, size_t ws_size,
                              hipStream_t stream)
{
    const float* conv = (const float*)d_in[0];
    const int*   pos  = (const int*)d_in[1];
    float*       out  = (float*)d_out;

    const int B = in_sizes[0] / (S * Fn);   // 2048
    pmax_kernel<<<B, 256, 0, stream>>>(conv, pos, out);
}

// Round 4
// 81.532 us; speedup vs baseline: 1.2507x; 1.1223x over previous
//
#include <hip/hip_runtime.h>

// piecewise max-pool: conv [B, S=256, F=230] f32, positions [B,4] i32 -> out [B, 3*230] f32
// Per batch b: e1=pos[b][1], e2=pos[b][3]; max over s-ranges [0,e1), [e1,e2), [e2,S).
//
// R4: same as R3 (float4 flat-chunk mapping) but with ext_vector_type(4) float for
// __builtin_nontemporal_load (HIP_vector_type rejected by the builtin).
// 4 rows = 920 floats = 3680 B -> 16B-aligned chunk stride; thread t owns flat slots
// [4t,4t+4) of every 4-row chunk: all loads are global_load_dwordx4 nt, and each
// thread keeps the same filter slots across all 64 chunks (register accumulation).

constexpr int S   = 256;
constexpr int Fn  = 230;
constexpr int RPC = 4;                 // rows per chunk
constexpr int CF  = Fn * RPC;          // 920 floats per chunk
constexpr int NCH = S / RPC;           // 64 chunks
constexpr int NT  = CF / 4;            // 230 active threads
constexpr float NEG = -1e30f;

typedef float f32x4 __attribute__((ext_vector_type(4)));

__global__ __launch_bounds__(256) void pmax_kernel(
    const float* __restrict__ conv,
    const int*   __restrict__ pos,
    float*       __restrict__ out)
{
    const int b = blockIdx.x;
    const int t = threadIdx.x;
    const int e1 = pos[b * 4 + 1];
    const int e2 = pos[b * 4 + 3];
    const float* base = conv + (size_t)b * (S * Fn);

    float m[3][4];
    #pragma unroll
    for (int p = 0; p < 3; ++p)
        #pragma unroll
        for (int j = 0; j < 4; ++j) m[p][j] = NEG;

    if (t < NT) {
        // element j sits in row-in-chunk rj; global s = 4g + rj.
        // s < e  <=>  4g < e - rj
        int a1[4], a2[4];
        #pragma unroll
        for (int j = 0; j < 4; ++j) {
            const int rj = (4 * t + j) / Fn;     // 0..3, thread-constant
            a1[j] = e1 - rj;
            a2[j] = e2 - rj;
        }
        const float* p0 = base + 4 * t;          // 16B aligned

        #pragma unroll 4
        for (int g = 0; g < NCH; ++g) {
            const f32x4 v = __builtin_nontemporal_load(
                (const f32x4*)(p0 + (size_t)g * CF));
            const int s4 = 4 * g;
            #pragma unroll
            for (int j = 0; j < 4; ++j) {
                const float vj = v[j];
                const bool c1 = s4 < a1[j];      // piece 0
                const bool c2 = s4 < a2[j];      // piece 0 or 1
                m[0][j] = fmaxf(m[0][j], c1 ? vj : NEG);
                m[1][j] = fmaxf(m[1][j], c2 ? (c1 ? NEG : vj) : NEG);
                m[2][j] = fmaxf(m[2][j], c2 ? NEG : vj);
            }
        }
    }

    // combine the 4 row-parities per filter: scatter to LDS by flat slot,
    // then filter f = max over slots {f, f+230, f+460, f+690}.
    __shared__ float lds[3][CF];
    if (t < NT) {
        #pragma unroll
        for (int p = 0; p < 3; ++p) {
            lds[p][4 * t + 0] = m[p][0];
            lds[p][4 * t + 1] = m[p][1];
            lds[p][4 * t + 2] = m[p][2];
            lds[p][4 * t + 3] = m[p][3];
        }
    }
    __syncthreads();
    if (t < Fn) {
        float* ob = out + (size_t)b * (3 * Fn);
        #pragma unroll
        for (int p = 0; p < 3; ++p) {
            const float mm = fmaxf(fmaxf(lds[p][t],          lds[p][t + Fn]),
                                   fmaxf(lds[p][t + 2 * Fn], lds[p][t + 3 * Fn]));
            __builtin_nontemporal_store(mm, ob + p * Fn + t);
        }
    }
}

extern "C" void kernel_launch(void* const* d_in, const int* in_sizes, int n_in,
                              void* d_out, int out_size, void* d_ws, size_t ws_size,
                              hipStream_t stream)
{
    const float* conv = (const float*)d_in[0];
    const int*   pos  = (const int*)d_in[1];
    float*       out  = (float*)d_out;

    const int B = in_sizes[0] / (S * Fn);   // 2048
    pmax_kernel<<<B, 256, 0, stream>>>(conv, pos, out);
}